// Round 3
// baseline (428.783 us; speedup 1.0000x reference)
//
#include <hip/hip_runtime.h>
#include <hip/hip_bf16.h>

// GAT layer: out[i] = sum_{e: src=i} (adj[e] * alpha[e]) * h0[dst[e]],
// alpha = edge-softmax over outgoing edges of src, scores LeakyReLU(0.05).
// N=100000 nodes, F=128, H=64, E=1.6M edges. All fp32.
//
// Round-3 structure: all random-access WRITES converted to either coalesced
// writes (alpha, h_edge) or a single int2 scatter stream (dst,val) -> CSR.

#define LEAKY 0.05f

__device__ __forceinline__ float wave_reduce_sum_f(float v) {
#pragma unroll
    for (int off = 1; off < 64; off <<= 1) v += __shfl_xor(v, off);
    return v;
}
__device__ __forceinline__ int wave_reduce_sum_i(int v) {
#pragma unroll
    for (int off = 1; off < 64; off <<= 1) v += __shfl_xor(v, off);
    return v;
}
__device__ __forceinline__ int wave_scan_incl(int v, int lane) {
#pragma unroll
    for (int off = 1; off < 64; off <<= 1) {
        int u = __shfl_up(v, off);
        if (lane >= off) v += u;
    }
    return v;
}

// ---------------------------------------------------------------------------
// K1: h0 = x @ fc_w^T [N,64]; s_src[i]=h0[i]@a_w[:64]+a_b; s_dst[i]=h0[i]@a_w[64:]
__global__ __launch_bounds__(256, 4) void k_linear(
    const float* __restrict__ x, const float* __restrict__ fc_w,
    const float* __restrict__ a_w, const float* __restrict__ a_b,
    float* __restrict__ h0, float* __restrict__ s_src, float* __restrict__ s_dst,
    int N)
{
    __shared__ float4 wT[32][64];   // 32 KB
    __shared__ float4 xs[16][32];   // 8 KB

    const int tid = threadIdx.x;
    for (int idx = tid; idx < 64 * 32; idx += 256) {
        int f = idx >> 5, g = idx & 31;
        wT[g][f] = *(const float4*)&fc_w[f * 128 + g * 4];
    }

    const int wave = tid >> 6, lane = tid & 63;
    const float aw0 = a_w[lane];
    const float aw1 = a_w[64 + lane];
    const float ab  = a_b[0];

    for (int base = blockIdx.x * 16; base < N; base += gridDim.x * 16) {
        __syncthreads();
        const int nrows = min(16, N - base);
        for (int idx = tid; idx < nrows * 32; idx += 256) {
            int r = idx >> 5, c = idx & 31;
            xs[r][c] = *(const float4*)&x[(size_t)(base + r) * 128 + c * 4];
        }
        __syncthreads();

        const int r0 = wave * 4;
        float acc[4] = {0.f, 0.f, 0.f, 0.f};
#pragma unroll 4
        for (int g = 0; g < 32; ++g) {
            float4 w = wT[g][lane];
#pragma unroll
            for (int n = 0; n < 4; ++n) {
                float4 xv = xs[r0 + n][g];
                acc[n] += w.x * xv.x + w.y * xv.y + w.z * xv.z + w.w * xv.w;
            }
        }
#pragma unroll
        for (int n = 0; n < 4; ++n) {
            int i = base + r0 + n;
            if (i >= N) break;
            h0[(size_t)i * 64 + lane] = acc[n];
            float p0 = wave_reduce_sum_f(acc[n] * aw0);
            float p1 = wave_reduce_sum_f(acc[n] * aw1);
            if (lane == 0) { s_src[i] = p0 + ab; s_dst[i] = p1; }
        }
    }
}

// ---------------------------------------------------------------------------
// K2: edge pass — h_edge, degree, softmax denominator (fused)
__global__ __launch_bounds__(256) void k_edge(
    const int* __restrict__ src, const int* __restrict__ dst,
    const float* __restrict__ s_src, const float* __restrict__ s_dst,
    int* __restrict__ deg, float* __restrict__ h_sum,
    float* __restrict__ h_edge, int E)
{
    int e = blockIdx.x * 256 + threadIdx.x;
    if (e >= E) return;
    int s = src[e], d = dst[e];
    float t = s_src[s] + s_dst[d];       // a_b folded into s_src
    t = (t >= 0.f) ? t : LEAKY * t;
    float h = __expf(t);
    h_edge[e] = h;
    atomicAdd(&deg[s], 1);
    atomicAdd(&h_sum[s], h);
}

// ---------------------------------------------------------------------------
// K3a/b/c: hierarchical exclusive scan of deg -> row_ptr, cursor
__global__ __launch_bounds__(256) void k_scan_partial(
    const int* __restrict__ deg, int* __restrict__ blk_sum, int N)
{
    __shared__ int ws[4];
    const int i = blockIdx.x * 256 + threadIdx.x;
    const int wave = threadIdx.x >> 6, lane = threadIdx.x & 63;
    int v = (i < N) ? deg[i] : 0;
    v = wave_reduce_sum_i(v);
    if (lane == 0) ws[wave] = v;
    __syncthreads();
    if (threadIdx.x == 0) blk_sum[blockIdx.x] = ws[0] + ws[1] + ws[2] + ws[3];
}

__global__ __launch_bounds__(512) void k_scan_top(
    const int* __restrict__ blk_sum, int* __restrict__ blk_off, int G)
{
    __shared__ int ws[8];
    __shared__ int s_carry;
    const int t = threadIdx.x, wave = t >> 6, lane = t & 63;
    if (t == 0) s_carry = 0;
    __syncthreads();
    for (int base = 0; base < G; base += 512) {
        int idx = base + t;
        int orig = (idx < G) ? blk_sum[idx] : 0;
        int incl = wave_scan_incl(orig, lane);
        if (lane == 63) ws[wave] = incl;
        __syncthreads();
        int woff = 0;
        for (int w = 0; w < wave; ++w) woff += ws[w];
        int carry = s_carry;
        if (idx < G) blk_off[idx] = carry + woff + incl - orig;
        __syncthreads();
        if (t == 511) s_carry = carry + woff + incl;
        __syncthreads();
    }
}

__global__ __launch_bounds__(256) void k_scan_final(
    const int* __restrict__ deg, const int* __restrict__ blk_off,
    int* __restrict__ row_ptr, int* __restrict__ cursor, int N, int E)
{
    __shared__ int ws[4];
    const int i = blockIdx.x * 256 + threadIdx.x;
    const int wave = threadIdx.x >> 6, lane = threadIdx.x & 63;
    int orig = (i < N) ? deg[i] : 0;
    int incl = wave_scan_incl(orig, lane);
    if (lane == 63) ws[wave] = incl;
    __syncthreads();
    int woff = 0;
    for (int w = 0; w < wave; ++w) woff += ws[w];
    if (i < N) {
        int val = blk_off[blockIdx.x] + woff + incl - orig;
        row_ptr[i] = val;
        cursor[i]  = val;
    }
    if (i == 0) row_ptr[N] = E;
}

// ---------------------------------------------------------------------------
// K4: alpha (coalesced write) + single-stream scatter of (dst, val) into CSR
__global__ __launch_bounds__(256) void k_scatter2(
    const int* __restrict__ src, const int* __restrict__ dst,
    const float* __restrict__ adj, const float* __restrict__ h_edge,
    const float* __restrict__ h_sum, int* __restrict__ cursor,
    float* __restrict__ alpha_out, int2* __restrict__ dv_csr, int E)
{
    int e = blockIdx.x * 256 + threadIdx.x;
    if (e >= E) return;
    int s = src[e];
    float a = h_edge[e] / h_sum[s];
    alpha_out[e] = a;                      // coalesced (d_out alpha region)
    float val = adj[e] * a;
    int pos = atomicAdd(&cursor[s], 1);
    dv_csr[pos] = make_int2(dst[e], __float_as_int(val));
}

// ---------------------------------------------------------------------------
// K5: pure consumer — out[i] = sum_csr val * h0[dst]. One wave per node.
__global__ __launch_bounds__(256) void k_node2(
    const int* __restrict__ row_ptr, const int2* __restrict__ dv_csr,
    const float* __restrict__ h0, float* __restrict__ out, int N)
{
    const int wave = threadIdx.x >> 6, lane = threadIdx.x & 63;
    const int i = blockIdx.x * 4 + wave;
    if (i >= N) return;

    const int start = row_ptr[i];
    const int end   = row_ptr[i + 1];

    float acc = 0.f;
    for (int base = start; base < end; base += 64) {
        const int j = base + lane;
        const int m = min(64, end - base);
        int dd = 0; float val = 0.f;
        if (j < end) {
            int2 dv = dv_csr[j];
            dd  = dv.x;
            val = __int_as_float(dv.y);
        }
        for (int jj = 0; jj < m; ++jj) {
            float v  = __shfl(val, jj);
            int   d2 = __shfl(dd, jj);
            acc += v * h0[(size_t)d2 * 64 + lane];
        }
    }
    out[(size_t)i * 64 + lane] = acc;
}

// ---------------------------------------------------------------------------
extern "C" void kernel_launch(void* const* d_in, const int* in_sizes, int n_in,
                              void* d_out, int out_size, void* d_ws, size_t ws_size,
                              hipStream_t stream)
{
    const float* x     = (const float*)d_in[0];
    const int*   ei    = (const int*)d_in[1];
    const float* adj   = (const float*)d_in[2];
    const float* fc_w  = (const float*)d_in[3];
    const float* a_w   = (const float*)d_in[4];
    const float* a_b   = (const float*)d_in[5];

    const int N = in_sizes[0] / 128;   // 100000
    const int E = in_sizes[2];         // 1600000
    const int* src = ei;
    const int* dst = ei + E;

    float* out   = (float*)d_out;
    float* alpha = out + (size_t)N * 64;

    char* w = (char*)d_ws;
    auto carve = [&](size_t bytes) {
        char* p = w;
        w += (bytes + 255) & ~(size_t)255;
        return p;
    };
    float* h0      = (float*)carve((size_t)N * 64 * 4);
    float* s_src   = (float*)carve((size_t)N * 4);
    float* s_dst   = (float*)carve((size_t)N * 4);
    int*   deg     = (int*)  carve((size_t)N * 4);
    float* h_sum   = (float*)carve((size_t)N * 4);
    int*   row_ptr = (int*)  carve((size_t)(N + 1) * 4);
    int*   cursor  = (int*)  carve((size_t)N * 4);
    int*   blk_sum = (int*)  carve((size_t)((N + 255) / 256) * 4);
    int*   blk_off = (int*)  carve((size_t)((N + 255) / 256) * 4);
    float* h_edge  = (float*)carve((size_t)E * 4);
    int2*  dv_csr  = (int2*) carve((size_t)E * 8);

    hipMemsetAsync(deg, 0, (size_t)N * 4, stream);
    hipMemsetAsync(h_sum, 0, (size_t)N * 4, stream);

    k_linear<<<2048, 256, 0, stream>>>(x, fc_w, a_w, a_b, h0, s_src, s_dst, N);

    const int egrid = (E + 255) / 256;
    const int ngrid = (N + 255) / 256;   // 391
    k_edge<<<egrid, 256, 0, stream>>>(src, dst, s_src, s_dst, deg, h_sum, h_edge, E);
    k_scan_partial<<<ngrid, 256, 0, stream>>>(deg, blk_sum, N);
    k_scan_top<<<1, 512, 0, stream>>>(blk_sum, blk_off, ngrid);
    k_scan_final<<<ngrid, 256, 0, stream>>>(deg, blk_off, row_ptr, cursor, N, E);
    k_scatter2<<<egrid, 256, 0, stream>>>(src, dst, adj, h_edge, h_sum, cursor,
                                          alpha, dv_csr, E);
    k_node2<<<(N + 3) / 4, 256, 0, stream>>>(row_ptr, dv_csr, h0, out, N);
}

// Round 4
// 323.725 us; speedup vs baseline: 1.3245x; 1.3245x over previous
//
#include <hip/hip_runtime.h>
#include <hip/hip_bf16.h>

// GAT layer, round 4: zero global random atomics. Two-level radix partition
// (391 buckets of 256 nodes) -> per-bucket LDS-resident CSR -> fused gather.
// N=100000, F=128, H=64, E=1.6M. All fp32.

#define LEAKY 0.05f
#define BSH   8                  // nodes per bucket = 256
#define EPB   4096               // edges per edge-pass block
#define MAXIT 12
#define CAP   (MAXIT * 512)      // 6144 records max in fast path (~96 sigma)

__device__ __forceinline__ float wave_reduce_sum_f(float v) {
#pragma unroll
    for (int off = 1; off < 64; off <<= 1) v += __shfl_xor(v, off);
    return v;
}
__device__ __forceinline__ int wave_scan_incl(int v, int lane) {
#pragma unroll
    for (int off = 1; off < 64; off <<= 1) {
        int u = __shfl_up(v, off);
        if (lane >= off) v += u;
    }
    return v;
}

// ---------------------------------------------------------------------------
// K1: h0 = x @ fc_w^T [N,64]; s_src = h0@a_w[:64]+a_b; s_dst = h0@a_w[64:]
__global__ __launch_bounds__(256, 4) void k_linear(
    const float* __restrict__ x, const float* __restrict__ fc_w,
    const float* __restrict__ a_w, const float* __restrict__ a_b,
    float* __restrict__ h0, float* __restrict__ s_src, float* __restrict__ s_dst,
    int N)
{
    __shared__ float4 wT[32][64];
    __shared__ float4 xs[16][32];

    const int tid = threadIdx.x;
    for (int idx = tid; idx < 64 * 32; idx += 256) {
        int f = idx >> 5, g = idx & 31;
        wT[g][f] = *(const float4*)&fc_w[f * 128 + g * 4];
    }

    const int wave = tid >> 6, lane = tid & 63;
    const float aw0 = a_w[lane];
    const float aw1 = a_w[64 + lane];
    const float ab  = a_b[0];

    for (int base = blockIdx.x * 16; base < N; base += gridDim.x * 16) {
        __syncthreads();
        const int nrows = min(16, N - base);
        for (int idx = tid; idx < nrows * 32; idx += 256) {
            int r = idx >> 5, c = idx & 31;
            xs[r][c] = *(const float4*)&x[(size_t)(base + r) * 128 + c * 4];
        }
        __syncthreads();

        const int r0 = wave * 4;
        float acc[4] = {0.f, 0.f, 0.f, 0.f};
#pragma unroll 4
        for (int g = 0; g < 32; ++g) {
            float4 w = wT[g][lane];
#pragma unroll
            for (int n = 0; n < 4; ++n) {
                float4 xv = xs[r0 + n][g];
                acc[n] += w.x * xv.x + w.y * xv.y + w.z * xv.z + w.w * xv.w;
            }
        }
#pragma unroll
        for (int n = 0; n < 4; ++n) {
            int i = base + r0 + n;
            if (i >= N) break;
            h0[(size_t)i * 64 + lane] = acc[n];
            float p0 = wave_reduce_sum_f(acc[n] * aw0);
            float p1 = wave_reduce_sum_f(acc[n] * aw1);
            if (lane == 0) { s_src[i] = p0 + ab; s_dst[i] = p1; }
        }
    }
}

// ---------------------------------------------------------------------------
// K2: h_edge (coalesced) + per-block bucket histogram (no global atomics)
__global__ __launch_bounds__(256) void k_edge_h(
    const int* __restrict__ src, const int* __restrict__ dst,
    const float* __restrict__ s_src, const float* __restrict__ s_dst,
    float* __restrict__ h_edge, int* __restrict__ Hist, int E, int NB)
{
    __shared__ int hist[512];
    for (int b = threadIdx.x; b < NB; b += 256) hist[b] = 0;
    __syncthreads();
    const int e0 = blockIdx.x * EPB;
#pragma unroll
    for (int k = 0; k < EPB / 256; ++k) {
        int e = e0 + k * 256 + threadIdx.x;
        if (e < E) {
            int s = src[e], d = dst[e];
            float t = s_src[s] + s_dst[d];     // a_b folded into s_src
            t = (t >= 0.f) ? t : LEAKY * t;
            h_edge[e] = __expf(t);
            atomicAdd(&hist[s >> BSH], 1);     // LDS atomic only
        }
    }
    __syncthreads();
    for (int b = threadIdx.x; b < NB; b += 256)
        Hist[blockIdx.x * NB + b] = hist[b];
}

// ---------------------------------------------------------------------------
// K3: column scan of Hist -> Base[blk][b] (excl prefix within column) + coltot
// assumes NEB <= 512
__global__ __launch_bounds__(512) void k_colscan(
    const int* __restrict__ Hist, int* __restrict__ Base,
    int* __restrict__ coltot, int NEB, int NB)
{
    __shared__ int wsum[8];
    const int b = blockIdx.x;
    const int t = threadIdx.x, wave = t >> 6, lane = t & 63;
    int v = (t < NEB) ? Hist[t * NB + b] : 0;
    int incl = wave_scan_incl(v, lane);
    if (lane == 63) wsum[wave] = incl;
    __syncthreads();
    int woff = 0;
    for (int w = 0; w < wave; ++w) woff += wsum[w];
    if (t < NEB) Base[t * NB + b] = woff + incl - v;
    if (t == NEB - 1) coltot[b] = woff + incl;
}

// K4: exclusive scan of coltot -> boff (assumes NB <= 512)
__global__ __launch_bounds__(512) void k_boff(
    const int* __restrict__ coltot, int* __restrict__ boff, int NB, int E)
{
    __shared__ int wsum[8];
    const int t = threadIdx.x, wave = t >> 6, lane = t & 63;
    int v = (t < NB) ? coltot[t] : 0;
    int incl = wave_scan_incl(v, lane);
    if (lane == 63) wsum[wave] = incl;
    __syncthreads();
    int woff = 0;
    for (int w = 0; w < wave; ++w) woff += wsum[w];
    if (t < NB) boff[t] = woff + incl - v;
    if (t == 0) boff[NB] = E;
}

// ---------------------------------------------------------------------------
// K5: bin edges into bucket streams at precomputed bases (LDS cursors only).
// record: {dst, h_bits, val_bits, src_low}
__global__ __launch_bounds__(256) void k_bin(
    const int* __restrict__ src, const int* __restrict__ dst,
    const float* __restrict__ adj, const float* __restrict__ h_edge,
    const int* __restrict__ boff, const int* __restrict__ Base,
    int4* __restrict__ binned, int E, int NB)
{
    __shared__ int cur[512];
    for (int b = threadIdx.x; b < NB; b += 256)
        cur[b] = boff[b] + Base[blockIdx.x * NB + b];
    __syncthreads();
    const int e0 = blockIdx.x * EPB;
#pragma unroll
    for (int k = 0; k < EPB / 256; ++k) {
        int e = e0 + k * 256 + threadIdx.x;
        if (e < E) {
            int s = src[e];
            float h = h_edge[e];
            float v = h * adj[e];
            int pos = atomicAdd(&cur[s >> BSH], 1);
            binned[pos] = make_int4(dst[e], __float_as_int(h),
                                    __float_as_int(v), s & ((1 << BSH) - 1));
        }
    }
}

// ---------------------------------------------------------------------------
// K6: per-bucket: records -> regs -> LDS histogram/scan -> LDS CSR -> gather h0
// -> out (coalesced). h_sum via LDS atomics -> coalesced global write.
__global__ __launch_bounds__(512) void k_bucket(
    const int4* __restrict__ binned, const int* __restrict__ boff,
    const float* __restrict__ h0, float* __restrict__ out,
    float* __restrict__ h_sum_g, int N)
{
    __shared__ int   deg[256];
    __shared__ int   pref[257];
    __shared__ int   cursor[256];
    __shared__ float hsumS[256];
    __shared__ int2  rec[CAP];
    __shared__ int   wsum[8];

    const int b  = blockIdx.x;
    const int lo = boff[b], hi = boff[b + 1], cnt = hi - lo;
    const int n0 = b << BSH;
    const int nn = min(256, N - n0);
    const int t = threadIdx.x, wave = t >> 6, lane = t & 63;

    if (t < 256) { deg[t] = 0; hsumS[t] = 0.f; }
    __syncthreads();

    if (cnt <= CAP) {
        int4 r[MAXIT];
#pragma unroll
        for (int it = 0; it < MAXIT; ++it) {
            int j = lo + it * 512 + t;
            if (j < hi) r[it] = binned[j];
        }
#pragma unroll
        for (int it = 0; it < MAXIT; ++it)
            if (lo + it * 512 + t < hi) atomicAdd(&deg[r[it].w], 1);
        __syncthreads();

        // block scan of deg[0..255] (all waves run shfl; only first 4 matter)
        {
            int v = (t < 256) ? deg[t] : 0;
            int incl = wave_scan_incl(v, lane);
            if (t < 256 && lane == 63) wsum[wave] = incl;
            __syncthreads();
            if (t < 256) {
                int woff = 0;
                for (int w = 0; w < wave; ++w) woff += wsum[w];
                int p = woff + incl;
                pref[t + 1] = p;
                cursor[t]   = p - v;
                if (t == 0) pref[0] = 0;
            }
            __syncthreads();
        }

        // scatter into LDS CSR + h_sum accumulate
#pragma unroll
        for (int it = 0; it < MAXIT; ++it) {
            if (lo + it * 512 + t < hi) {
                int4 rr = r[it];
                int pos = atomicAdd(&cursor[rr.w], 1);
                rec[pos] = make_int2(rr.x, rr.z);
                atomicAdd(&hsumS[rr.w], __int_as_float(rr.y));
            }
        }
        __syncthreads();

        // per-node gather-accumulate; lane = feature
        for (int n = wave; n < nn; n += 8) {
            const int s = pref[n], e2 = pref[n + 1];
            float acc = 0.f;
            for (int j = s; j < e2; ++j) {
                int2 rv = rec[j];                       // LDS broadcast
                acc += __int_as_float(rv.y) * h0[(size_t)rv.x * 64 + lane];
            }
            float hs = hsumS[n];
            out[(size_t)(n0 + n) * 64 + lane] = (e2 > s) ? acc / hs : 0.f;
            if (lane == 0) h_sum_g[n0 + n] = hs;
        }
    } else {
        // correctness-only fallback (cnt > CAP is ~96 sigma; never expected)
        for (int n = wave; n < nn; n += 8) {
            float acc = 0.f, hs = 0.f;
            for (int j = lo; j < hi; ++j) {
                int4 rr = binned[j];
                if (rr.w == n) {
                    hs  += __int_as_float(rr.y);
                    acc += __int_as_float(rr.z) * h0[(size_t)rr.x * 64 + lane];
                }
            }
            out[(size_t)(n0 + n) * 64 + lane] = (hs > 0.f) ? acc / hs : 0.f;
            if (lane == 0) h_sum_g[n0 + n] = hs;
        }
    }
}

// ---------------------------------------------------------------------------
// K7: alpha[e] = h_edge[e] / h_sum[src[e]]  (coalesced, vectorized x4)
__global__ __launch_bounds__(256) void k_alpha(
    const float* __restrict__ h_edge, const int* __restrict__ src,
    const float* __restrict__ h_sum_g, float* __restrict__ alpha, int E)
{
    int i = blockIdx.x * 256 + threadIdx.x;
    int e = i * 4;
    if (e + 3 < E) {
        float4 h4 = *(const float4*)&h_edge[e];
        int4   s4 = *(const int4*)&src[e];
        float4 a;
        a.x = h4.x / h_sum_g[s4.x];
        a.y = h4.y / h_sum_g[s4.y];
        a.z = h4.z / h_sum_g[s4.z];
        a.w = h4.w / h_sum_g[s4.w];
        *(float4*)&alpha[e] = a;
    } else {
        for (; e < E; ++e) alpha[e] = h_edge[e] / h_sum_g[src[e]];
    }
}

// ---------------------------------------------------------------------------
extern "C" void kernel_launch(void* const* d_in, const int* in_sizes, int n_in,
                              void* d_out, int out_size, void* d_ws, size_t ws_size,
                              hipStream_t stream)
{
    const float* x    = (const float*)d_in[0];
    const int*   ei   = (const int*)d_in[1];
    const float* adj  = (const float*)d_in[2];
    const float* fc_w = (const float*)d_in[3];
    const float* a_w  = (const float*)d_in[4];
    const float* a_b  = (const float*)d_in[5];

    const int N = in_sizes[0] / 128;          // 100000
    const int E = in_sizes[2];                // 1600000
    const int* src = ei;
    const int* dst = ei + E;

    const int NB  = (N + 255) >> BSH;         // 391 buckets
    const int NEB = (E + EPB - 1) / EPB;      // 391 edge blocks

    float* out   = (float*)d_out;
    float* alpha = out + (size_t)N * 64;

    char* w = (char*)d_ws;
    auto carve = [&](size_t bytes) {
        char* p = w;
        w += (bytes + 255) & ~(size_t)255;
        return p;
    };
    float* h0      = (float*)carve((size_t)N * 64 * 4);
    float* s_src   = (float*)carve((size_t)N * 4);
    float* s_dst   = (float*)carve((size_t)N * 4);
    float* h_edge  = (float*)carve((size_t)E * 4);
    float* h_sum_g = (float*)carve((size_t)N * 4);
    int*   Hist    = (int*)  carve((size_t)NEB * NB * 4);
    int*   Base    = (int*)  carve((size_t)NEB * NB * 4);
    int*   coltot  = (int*)  carve((size_t)NB * 4);
    int*   boff    = (int*)  carve((size_t)(NB + 1) * 4);
    int4*  binned  = (int4*) carve((size_t)E * 16);

    k_linear<<<2048, 256, 0, stream>>>(x, fc_w, a_w, a_b, h0, s_src, s_dst, N);
    k_edge_h<<<NEB, 256, 0, stream>>>(src, dst, s_src, s_dst, h_edge, Hist, E, NB);
    k_colscan<<<NB, 512, 0, stream>>>(Hist, Base, coltot, NEB, NB);
    k_boff<<<1, 512, 0, stream>>>(coltot, boff, NB, E);
    k_bin<<<NEB, 256, 0, stream>>>(src, dst, adj, h_edge, boff, Base, binned, E, NB);
    k_bucket<<<NB, 512, 0, stream>>>(binned, boff, h0, out, h_sum_g, N);
    k_alpha<<<(E / 4 + 255) / 256, 256, 0, stream>>>(h_edge, src, h_sum_g, alpha, E);
}

// Round 5
// 177.345 us; speedup vs baseline: 2.4178x; 1.8254x over previous
//
#include <hip/hip_runtime.h>
#include <hip/hip_bf16.h>

// GAT layer, round 5: radix partition into 782 buckets of 128 nodes,
// bf16 h0 gather rows (1 cache line), int2 edge records, 4-deep ILP gather.
// N=100000, F=128, H=64, E=1.6M.

#define LEAKY 0.05f
#define BSH   7                  // nodes per bucket = 128
#define BSZ   128
#define EPB   8192               // edges per edge-pass block
#define MAXIT 5
#define CAPB  (MAXIT * 512)      // 2560 records fast-path cap (mean 2048, +11 sigma)

__device__ __forceinline__ float wave_reduce_sum_f(float v) {
#pragma unroll
    for (int off = 1; off < 64; off <<= 1) v += __shfl_xor(v, off);
    return v;
}
__device__ __forceinline__ int wave_scan_incl(int v, int lane) {
#pragma unroll
    for (int off = 1; off < 64; off <<= 1) {
        int u = __shfl_up(v, off);
        if (lane >= off) v += u;
    }
    return v;
}
__device__ __forceinline__ unsigned short f2bf(float f) {   // RNE bf16
    unsigned u = __float_as_uint(f);
    return (unsigned short)((u + 0x7FFF + ((u >> 16) & 1)) >> 16);
}
__device__ __forceinline__ float bf2f(unsigned short u) {
    return __uint_as_float((unsigned)u << 16);
}

// ---------------------------------------------------------------------------
// K1: h0b = bf16(x @ fc_w^T); s_src = h0@a_w[:64]+a_b; s_dst = h0@a_w[64:]
__global__ __launch_bounds__(256, 4) void k_linear(
    const float* __restrict__ x, const float* __restrict__ fc_w,
    const float* __restrict__ a_w, const float* __restrict__ a_b,
    unsigned short* __restrict__ h0b, float* __restrict__ s_src,
    float* __restrict__ s_dst, int N)
{
    __shared__ float4 wT[32][64];
    __shared__ float4 xs[16][32];

    const int tid = threadIdx.x;
    for (int idx = tid; idx < 64 * 32; idx += 256) {
        int f = idx >> 5, g = idx & 31;
        wT[g][f] = *(const float4*)&fc_w[f * 128 + g * 4];
    }

    const int wave = tid >> 6, lane = tid & 63;
    const float aw0 = a_w[lane];
    const float aw1 = a_w[64 + lane];
    const float ab  = a_b[0];

    for (int base = blockIdx.x * 16; base < N; base += gridDim.x * 16) {
        __syncthreads();
        const int nrows = min(16, N - base);
        for (int idx = tid; idx < nrows * 32; idx += 256) {
            int r = idx >> 5, c = idx & 31;
            xs[r][c] = *(const float4*)&x[(size_t)(base + r) * 128 + c * 4];
        }
        __syncthreads();

        const int r0 = wave * 4;
        float acc[4] = {0.f, 0.f, 0.f, 0.f};
#pragma unroll 4
        for (int g = 0; g < 32; ++g) {
            float4 w = wT[g][lane];
#pragma unroll
            for (int n = 0; n < 4; ++n) {
                float4 xv = xs[r0 + n][g];
                acc[n] += w.x * xv.x + w.y * xv.y + w.z * xv.z + w.w * xv.w;
            }
        }
#pragma unroll
        for (int n = 0; n < 4; ++n) {
            int i = base + r0 + n;
            if (i >= N) break;
            h0b[(size_t)i * 64 + lane] = f2bf(acc[n]);
            float p0 = wave_reduce_sum_f(acc[n] * aw0);
            float p1 = wave_reduce_sum_f(acc[n] * aw1);
            if (lane == 0) { s_src[i] = p0 + ab; s_dst[i] = p1; }
        }
    }
}

// ---------------------------------------------------------------------------
// K2: h_edge (coalesced) + per-block bucket histogram (LDS atomics only)
__global__ __launch_bounds__(512) void k_edge_h(
    const int* __restrict__ src, const int* __restrict__ dst,
    const float* __restrict__ s_src, const float* __restrict__ s_dst,
    float* __restrict__ h_edge, int* __restrict__ Hist, int E, int NB)
{
    __shared__ int hist[1024];
    for (int b = threadIdx.x; b < NB; b += 512) hist[b] = 0;
    __syncthreads();
    const int e0 = blockIdx.x * EPB;
#pragma unroll
    for (int k = 0; k < EPB / 512; ++k) {
        int e = e0 + k * 512 + threadIdx.x;
        if (e < E) {
            int s = src[e], d = dst[e];
            float t = s_src[s] + s_dst[d];     // a_b folded into s_src
            t = (t >= 0.f) ? t : LEAKY * t;
            h_edge[e] = __expf(t);
            atomicAdd(&hist[s >> BSH], 1);
        }
    }
    __syncthreads();
    for (int b = threadIdx.x; b < NB; b += 512)
        Hist[blockIdx.x * NB + b] = hist[b];
}

// ---------------------------------------------------------------------------
// K3: column scan of Hist -> Base[blk][b] (excl prefix within column) + coltot
__global__ __launch_bounds__(512) void k_colscan(
    const int* __restrict__ Hist, int* __restrict__ Base,
    int* __restrict__ coltot, int NEB, int NB)
{
    __shared__ int wsum[8];
    const int b = blockIdx.x;
    const int t = threadIdx.x, wave = t >> 6, lane = t & 63;
    int v = (t < NEB) ? Hist[t * NB + b] : 0;
    int incl = wave_scan_incl(v, lane);
    if (lane == 63) wsum[wave] = incl;
    __syncthreads();
    int woff = 0;
    for (int w = 0; w < wave; ++w) woff += wsum[w];
    if (t < NEB) Base[t * NB + b] = woff + incl - v;
    if (t == NEB - 1) coltot[b] = woff + incl;
}

// K4: chunked exclusive scan of coltot[NB] -> boff (NB may exceed 512)
__global__ __launch_bounds__(512) void k_boff(
    const int* __restrict__ coltot, int* __restrict__ boff, int NB, int E)
{
    __shared__ int wsum[8];
    __shared__ int s_carry;
    const int t = threadIdx.x, wave = t >> 6, lane = t & 63;
    if (t == 0) s_carry = 0;
    __syncthreads();
    for (int base = 0; base < NB; base += 512) {
        int idx = base + t;
        int orig = (idx < NB) ? coltot[idx] : 0;
        int incl = wave_scan_incl(orig, lane);
        if (lane == 63) wsum[wave] = incl;
        __syncthreads();
        int woff = 0;
        for (int w = 0; w < wave; ++w) woff += wsum[w];
        int carry = s_carry;
        if (idx < NB) boff[idx] = carry + woff + incl - orig;
        __syncthreads();
        if (t == 511) s_carry = carry + woff + incl;
        __syncthreads();
    }
    if (t == 0) boff[NB] = E;
}

// ---------------------------------------------------------------------------
// K5: bin edges into bucket streams; record int2 {dst|srclow<<24, h_bf16|v_bf16}
__global__ __launch_bounds__(512) void k_bin(
    const int* __restrict__ src, const int* __restrict__ dst,
    const float* __restrict__ adj, const float* __restrict__ h_edge,
    const int* __restrict__ boff, const int* __restrict__ Base,
    int2* __restrict__ binned, int E, int NB)
{
    __shared__ int cur[1024];
    for (int b = threadIdx.x; b < NB; b += 512)
        cur[b] = boff[b] + Base[blockIdx.x * NB + b];
    __syncthreads();
    const int e0 = blockIdx.x * EPB;
#pragma unroll
    for (int k = 0; k < EPB / 512; ++k) {
        int e = e0 + k * 512 + threadIdx.x;
        if (e < E) {
            int s = src[e];
            float h = h_edge[e];
            float v = h * adj[e];
            unsigned hv = ((unsigned)f2bf(h) << 16) | f2bf(v);
            int w0 = dst[e] | ((s & (BSZ - 1)) << 24);
            int pos = atomicAdd(&cur[s >> BSH], 1);
            binned[pos] = make_int2(w0, (int)hv);
        }
    }
}

// ---------------------------------------------------------------------------
// K6: per-bucket LDS CSR build + fused gather. 512 thr, 8 waves, 128 nodes.
__global__ __launch_bounds__(512) void k_bucket(
    const int2* __restrict__ binned, const int* __restrict__ boff,
    const unsigned short* __restrict__ h0b, float* __restrict__ out,
    float* __restrict__ h_sum_g, int N)
{
    __shared__ int   deg_cur[BSZ];    // degree, then cursor
    __shared__ int   pref[BSZ + 1];
    __shared__ float hsumS[BSZ];
    __shared__ int2  rec[CAPB];       // {dst, val_fp32_bits}
    __shared__ int   wsum[8];

    const int b  = blockIdx.x;
    const int lo = boff[b], hi = boff[b + 1], cnt = hi - lo;
    const int n0 = b << BSH;
    const int nn = min(BSZ, N - n0);
    const int t = threadIdx.x, wave = t >> 6, lane = t & 63;

    if (t < BSZ) { deg_cur[t] = 0; hsumS[t] = 0.f; }
    __syncthreads();

    if (cnt <= CAPB) {
        int2 r[MAXIT];
#pragma unroll
        for (int it = 0; it < MAXIT; ++it) {
            int j = lo + it * 512 + t;
            if (j < hi) r[it] = binned[j];
        }
#pragma unroll
        for (int it = 0; it < MAXIT; ++it)
            if (lo + it * 512 + t < hi)
                atomicAdd(&deg_cur[(unsigned)r[it].x >> 24], 1);
        __syncthreads();

        // scan of deg[0..127] (waves 0-1)
        int v = (t < BSZ) ? deg_cur[t] : 0;
        int incl = wave_scan_incl(v, lane);
        if (t < BSZ && lane == 63) wsum[wave] = incl;
        __syncthreads();
        int p = 0;
        if (t < BSZ) {
            int woff = 0;
            for (int w = 0; w < wave; ++w) woff += wsum[w];
            p = woff + incl;
            pref[t + 1] = p;
            if (t == 0) pref[0] = 0;
        }
        __syncthreads();
        if (t < BSZ) deg_cur[t] = p - v;     // cursor = exclusive prefix
        __syncthreads();

        // scatter into LDS CSR + h_sum accumulate
#pragma unroll
        for (int it = 0; it < MAXIT; ++it) {
            if (lo + it * 512 + t < hi) {
                int2 rr = r[it];
                int node = (unsigned)rr.x >> 24;
                int d    = rr.x & 0xFFFFFF;
                float hh = __uint_as_float((unsigned)rr.y & 0xFFFF0000u);
                float vv = __uint_as_float((unsigned)rr.y << 16);
                int pos = atomicAdd(&deg_cur[node], 1);
                rec[pos] = make_int2(d, __float_as_int(vv));
                atomicAdd(&hsumS[node], hh);
            }
        }
        __syncthreads();

        // gather: lane = feature, 4-deep ILP
        for (int n = wave; n < nn; n += 8) {
            const int s = pref[n], e2 = pref[n + 1];
            float a0 = 0.f, a1 = 0.f, a2 = 0.f, a3 = 0.f;
            int j = s;
            for (; j + 4 <= e2; j += 4) {
                int2 q0 = rec[j], q1 = rec[j + 1], q2 = rec[j + 2], q3 = rec[j + 3];
                a0 += __int_as_float(q0.y) * bf2f(h0b[(size_t)q0.x * 64 + lane]);
                a1 += __int_as_float(q1.y) * bf2f(h0b[(size_t)q1.x * 64 + lane]);
                a2 += __int_as_float(q2.y) * bf2f(h0b[(size_t)q2.x * 64 + lane]);
                a3 += __int_as_float(q3.y) * bf2f(h0b[(size_t)q3.x * 64 + lane]);
            }
            for (; j < e2; ++j) {
                int2 q = rec[j];
                a0 += __int_as_float(q.y) * bf2f(h0b[(size_t)q.x * 64 + lane]);
            }
            float acc = (a0 + a1) + (a2 + a3);
            float hs = hsumS[n];
            out[(size_t)(n0 + n) * 64 + lane] = (e2 > s) ? acc / hs : 0.f;
            if (lane == 0) h_sum_g[n0 + n] = hs;
        }
    } else {
        // correctness-only fallback (cnt > CAPB is ~11 sigma; never expected)
        for (int n = wave; n < nn; n += 8) {
            float acc = 0.f, hs = 0.f;
            for (int j = lo; j < hi; ++j) {
                int2 rr = binned[j];
                if (((unsigned)rr.x >> 24) == (unsigned)n) {
                    hs  += __uint_as_float((unsigned)rr.y & 0xFFFF0000u);
                    acc += __uint_as_float((unsigned)rr.y << 16) *
                           bf2f(h0b[(size_t)(rr.x & 0xFFFFFF) * 64 + lane]);
                }
            }
            out[(size_t)(n0 + n) * 64 + lane] = (hs > 0.f) ? acc / hs : 0.f;
            if (lane == 0) h_sum_g[n0 + n] = hs;
        }
    }
}

// ---------------------------------------------------------------------------
// K7: alpha[e] = h_edge[e] / h_sum[src[e]]  (coalesced, x4)
__global__ __launch_bounds__(256) void k_alpha(
    const float* __restrict__ h_edge, const int* __restrict__ src,
    const float* __restrict__ h_sum_g, float* __restrict__ alpha, int E)
{
    int i = blockIdx.x * 256 + threadIdx.x;
    int e = i * 4;
    if (e + 3 < E) {
        float4 h4 = *(const float4*)&h_edge[e];
        int4   s4 = *(const int4*)&src[e];
        float4 a;
        a.x = h4.x / h_sum_g[s4.x];
        a.y = h4.y / h_sum_g[s4.y];
        a.z = h4.z / h_sum_g[s4.z];
        a.w = h4.w / h_sum_g[s4.w];
        *(float4*)&alpha[e] = a;
    } else {
        for (; e < E; ++e) alpha[e] = h_edge[e] / h_sum_g[src[e]];
    }
}

// ---------------------------------------------------------------------------
extern "C" void kernel_launch(void* const* d_in, const int* in_sizes, int n_in,
                              void* d_out, int out_size, void* d_ws, size_t ws_size,
                              hipStream_t stream)
{
    const float* x    = (const float*)d_in[0];
    const int*   ei   = (const int*)d_in[1];
    const float* adj  = (const float*)d_in[2];
    const float* fc_w = (const float*)d_in[3];
    const float* a_w  = (const float*)d_in[4];
    const float* a_b  = (const float*)d_in[5];

    const int N = in_sizes[0] / 128;          // 100000
    const int E = in_sizes[2];                // 1600000
    const int* src = ei;
    const int* dst = ei + E;

    const int NB  = (N + BSZ - 1) >> BSH;     // 782 buckets
    const int NEB = (E + EPB - 1) / EPB;      // 196 edge blocks

    float* out   = (float*)d_out;
    float* alpha = out + (size_t)N * 64;

    char* w = (char*)d_ws;
    auto carve = [&](size_t bytes) {
        char* p = w;
        w += (bytes + 255) & ~(size_t)255;
        return p;
    };
    unsigned short* h0b = (unsigned short*)carve((size_t)N * 64 * 2);
    float* s_src   = (float*)carve((size_t)N * 4);
    float* s_dst   = (float*)carve((size_t)N * 4);
    float* h_edge  = (float*)carve((size_t)E * 4);
    float* h_sum_g = (float*)carve((size_t)N * 4);
    int*   Hist    = (int*)  carve((size_t)NEB * NB * 4);
    int*   Base    = (int*)  carve((size_t)NEB * NB * 4);
    int*   coltot  = (int*)  carve((size_t)NB * 4);
    int*   boff    = (int*)  carve((size_t)(NB + 1) * 4);
    int2*  binned  = (int2*) carve((size_t)E * 8);

    k_linear<<<2048, 256, 0, stream>>>(x, fc_w, a_w, a_b, h0b, s_src, s_dst, N);
    k_edge_h<<<NEB, 512, 0, stream>>>(src, dst, s_src, s_dst, h_edge, Hist, E, NB);
    k_colscan<<<NB, 512, 0, stream>>>(Hist, Base, coltot, NEB, NB);
    k_boff<<<1, 512, 0, stream>>>(coltot, boff, NB, E);
    k_bin<<<NEB, 512, 0, stream>>>(src, dst, adj, h_edge, boff, Base, binned, E, NB);
    k_bucket<<<NB, 512, 0, stream>>>(binned, boff, h0b, out, h_sum_g, N);
    k_alpha<<<(E / 4 + 255) / 256, 256, 0, stream>>>(h_edge, src, h_sum_g, alpha, E);
}

// Round 6
// 154.208 us; speedup vs baseline: 2.7806x; 1.1500x over previous
//
#include <hip/hip_runtime.h>
#include <hip/hip_bf16.h>

// GAT layer, round 6: k_linear rewritten as MFMA bf16 GEMM (zero LDS),
// scores reduced from accumulator registers. Rest of pipeline unchanged:
// radix partition into 782 buckets of 128 nodes, LDS CSR, fused gather.
// N=100000, F=128, H=64, E=1.6M.

#define LEAKY 0.05f
#define BSH   7                  // nodes per bucket = 128
#define BSZ   128
#define EPB   8192               // edges per edge-pass block
#define MAXIT 5
#define CAPB  (MAXIT * 512)      // 2560 records fast-path cap (mean 2048, +11 sigma)

using bf16x8 = __attribute__((ext_vector_type(8))) __bf16;
using f32x4  = __attribute__((ext_vector_type(4))) float;

__device__ __forceinline__ int wave_scan_incl(int v, int lane) {
#pragma unroll
    for (int off = 1; off < 64; off <<= 1) {
        int u = __shfl_up(v, off);
        if (lane >= off) v += u;
    }
    return v;
}
__device__ __forceinline__ unsigned short f2bf(float f) {   // RNE bf16
    unsigned u = __float_as_uint(f);
    return (unsigned short)((u + 0x7FFF + ((u >> 16) & 1)) >> 16);
}
__device__ __forceinline__ float bf2f(unsigned short u) {
    return __uint_as_float((unsigned)u << 16);
}
__device__ __forceinline__ bf16x8 pack8(const float* p) {
    float4 lo = *(const float4*)p;
    float4 hi = *(const float4*)(p + 4);
    bf16x8 v;
    v[0] = (__bf16)lo.x; v[1] = (__bf16)lo.y; v[2] = (__bf16)lo.z; v[3] = (__bf16)lo.w;
    v[4] = (__bf16)hi.x; v[5] = (__bf16)hi.y; v[6] = (__bf16)hi.z; v[7] = (__bf16)hi.w;
    return v;
}

// ---------------------------------------------------------------------------
// K1: h0b = bf16(x @ fc_w^T) via mfma_f32_16x16x32_bf16; s_src/s_dst from regs.
// One wave = 16 nodes. A: row=lane&15, k=(lane>>4)*8+j. B: col=lane&15, same k.
// D: col=lane&15, row=(lane>>4)*4+reg  [m89-verified layout].
__global__ __launch_bounds__(256) void k_linear_mfma(
    const float* __restrict__ x, const float* __restrict__ fc_w,
    const float* __restrict__ a_w, const float* __restrict__ a_b,
    unsigned short* __restrict__ h0b, float* __restrict__ s_src,
    float* __restrict__ s_dst, int N)
{
    const int wave = threadIdx.x >> 6, lane = threadIdx.x & 63;
    const int row = lane & 15, grp = lane >> 4;

    // B fragments: bf[nt][kb], f = nt*16+row, k = kb*32+grp*8+j  (64 VGPR)
    bf16x8 bf[4][4];
#pragma unroll
    for (int nt = 0; nt < 4; ++nt) {
        const float* wrow = fc_w + (size_t)(nt * 16 + row) * 128;
#pragma unroll
        for (int kb = 0; kb < 4; ++kb)
            bf[nt][kb] = pack8(wrow + kb * 32 + grp * 8);
    }
    float aw0[4], aw1[4];
#pragma unroll
    for (int nt = 0; nt < 4; ++nt) {
        aw0[nt] = a_w[nt * 16 + row];
        aw1[nt] = a_w[64 + nt * 16 + row];
    }
    const float ab = a_b[0];

    const int tile = blockIdx.x * 4 + wave;
    const int base = tile * 16;
    if (base >= N) return;
    const int node = min(base + row, N - 1);

    // A fragments (4 VGPR each): 8 consecutive fp32 of this node's x row
    bf16x8 af[4];
#pragma unroll
    for (int kb = 0; kb < 4; ++kb)
        af[kb] = pack8(x + (size_t)node * 128 + kb * 32 + grp * 8);

    f32x4 acc[4];
#pragma unroll
    for (int nt = 0; nt < 4; ++nt) acc[nt] = (f32x4){0.f, 0.f, 0.f, 0.f};

#pragma unroll
    for (int nt = 0; nt < 4; ++nt)
#pragma unroll
        for (int kb = 0; kb < 4; ++kb)
            acc[nt] = __builtin_amdgcn_mfma_f32_16x16x32_bf16(
                af[kb], bf[nt][kb], acc[nt], 0, 0, 0);

    // h0b store: lane holds D[row=grp*4+r][col=row] of tile nt
#pragma unroll
    for (int nt = 0; nt < 4; ++nt)
#pragma unroll
        for (int r = 0; r < 4; ++r) {
            int nrow = base + grp * 4 + r;
            if (nrow < N)
                h0b[(size_t)nrow * 64 + nt * 16 + row] = f2bf(acc[nt][r]);
        }

    // scores: per output row, dot with a_w halves, reduce across 16-lane group
#pragma unroll
    for (int r = 0; r < 4; ++r) {
        float p0 = 0.f, p1 = 0.f;
#pragma unroll
        for (int nt = 0; nt < 4; ++nt) {
            p0 += acc[nt][r] * aw0[nt];
            p1 += acc[nt][r] * aw1[nt];
        }
#pragma unroll
        for (int off = 1; off < 16; off <<= 1) {
            p0 += __shfl_xor(p0, off);
            p1 += __shfl_xor(p1, off);
        }
        int nrow = base + grp * 4 + r;
        if (row == 0 && nrow < N) { s_src[nrow] = p0 + ab; s_dst[nrow] = p1; }
    }
}

// ---------------------------------------------------------------------------
// K2: h_edge (coalesced) + per-block bucket histogram (LDS atomics only)
__global__ __launch_bounds__(512) void k_edge_h(
    const int* __restrict__ src, const int* __restrict__ dst,
    const float* __restrict__ s_src, const float* __restrict__ s_dst,
    float* __restrict__ h_edge, int* __restrict__ Hist, int E, int NB)
{
    __shared__ int hist[1024];
    for (int b = threadIdx.x; b < NB; b += 512) hist[b] = 0;
    __syncthreads();
    const int e0 = blockIdx.x * EPB;
#pragma unroll
    for (int k = 0; k < EPB / 512; ++k) {
        int e = e0 + k * 512 + threadIdx.x;
        if (e < E) {
            int s = src[e], d = dst[e];
            float t = s_src[s] + s_dst[d];     // a_b folded into s_src
            t = (t >= 0.f) ? t : LEAKY * t;
            h_edge[e] = __expf(t);
            atomicAdd(&hist[s >> BSH], 1);
        }
    }
    __syncthreads();
    for (int b = threadIdx.x; b < NB; b += 512)
        Hist[blockIdx.x * NB + b] = hist[b];
}

// ---------------------------------------------------------------------------
// K3: column scan of Hist -> Base[blk][b] (excl prefix within column) + coltot
__global__ __launch_bounds__(512) void k_colscan(
    const int* __restrict__ Hist, int* __restrict__ Base,
    int* __restrict__ coltot, int NEB, int NB)
{
    __shared__ int wsum[8];
    const int b = blockIdx.x;
    const int t = threadIdx.x, wave = t >> 6, lane = t & 63;
    int v = (t < NEB) ? Hist[t * NB + b] : 0;
    int incl = wave_scan_incl(v, lane);
    if (lane == 63) wsum[wave] = incl;
    __syncthreads();
    int woff = 0;
    for (int w = 0; w < wave; ++w) woff += wsum[w];
    if (t < NEB) Base[t * NB + b] = woff + incl - v;
    if (t == NEB - 1) coltot[b] = woff + incl;
}

// K4: chunked exclusive scan of coltot[NB] -> boff
__global__ __launch_bounds__(512) void k_boff(
    const int* __restrict__ coltot, int* __restrict__ boff, int NB, int E)
{
    __shared__ int wsum[8];
    __shared__ int s_carry;
    const int t = threadIdx.x, wave = t >> 6, lane = t & 63;
    if (t == 0) s_carry = 0;
    __syncthreads();
    for (int base = 0; base < NB; base += 512) {
        int idx = base + t;
        int orig = (idx < NB) ? coltot[idx] : 0;
        int incl = wave_scan_incl(orig, lane);
        if (lane == 63) wsum[wave] = incl;
        __syncthreads();
        int woff = 0;
        for (int w = 0; w < wave; ++w) woff += wsum[w];
        int carry = s_carry;
        if (idx < NB) boff[idx] = carry + woff + incl - orig;
        __syncthreads();
        if (t == 511) s_carry = carry + woff + incl;
        __syncthreads();
    }
    if (t == 0) boff[NB] = E;
}

// ---------------------------------------------------------------------------
// K5: bin edges into bucket streams; record int2 {dst|srclow<<24, h_bf16|v_bf16}
__global__ __launch_bounds__(512) void k_bin(
    const int* __restrict__ src, const int* __restrict__ dst,
    const float* __restrict__ adj, const float* __restrict__ h_edge,
    const int* __restrict__ boff, const int* __restrict__ Base,
    int2* __restrict__ binned, int E, int NB)
{
    __shared__ int cur[1024];
    for (int b = threadIdx.x; b < NB; b += 512)
        cur[b] = boff[b] + Base[blockIdx.x * NB + b];
    __syncthreads();
    const int e0 = blockIdx.x * EPB;
#pragma unroll
    for (int k = 0; k < EPB / 512; ++k) {
        int e = e0 + k * 512 + threadIdx.x;
        if (e < E) {
            int s = src[e];
            float h = h_edge[e];
            float v = h * adj[e];
            unsigned hv = ((unsigned)f2bf(h) << 16) | f2bf(v);
            int w0 = dst[e] | ((s & (BSZ - 1)) << 24);
            int pos = atomicAdd(&cur[s >> BSH], 1);
            binned[pos] = make_int2(w0, (int)hv);
        }
    }
}

// ---------------------------------------------------------------------------
// K6: per-bucket LDS CSR build + fused gather. 512 thr, 8 waves, 128 nodes.
__global__ __launch_bounds__(512) void k_bucket(
    const int2* __restrict__ binned, const int* __restrict__ boff,
    const unsigned short* __restrict__ h0b, float* __restrict__ out,
    float* __restrict__ h_sum_g, int N)
{
    __shared__ int   deg_cur[BSZ];    // degree, then cursor
    __shared__ int   pref[BSZ + 1];
    __shared__ float hsumS[BSZ];
    __shared__ int2  rec[CAPB];       // {dst, val_fp32_bits}
    __shared__ int   wsum[8];

    const int b  = blockIdx.x;
    const int lo = boff[b], hi = boff[b + 1], cnt = hi - lo;
    const int n0 = b << BSH;
    const int nn = min(BSZ, N - n0);
    const int t = threadIdx.x, wave = t >> 6, lane = t & 63;

    if (t < BSZ) { deg_cur[t] = 0; hsumS[t] = 0.f; }
    __syncthreads();

    if (cnt <= CAPB) {
        int2 r[MAXIT];
#pragma unroll
        for (int it = 0; it < MAXIT; ++it) {
            int j = lo + it * 512 + t;
            if (j < hi) r[it] = binned[j];
        }
#pragma unroll
        for (int it = 0; it < MAXIT; ++it)
            if (lo + it * 512 + t < hi)
                atomicAdd(&deg_cur[(unsigned)r[it].x >> 24], 1);
        __syncthreads();

        int v = (t < BSZ) ? deg_cur[t] : 0;
        int incl = wave_scan_incl(v, lane);
        if (t < BSZ && lane == 63) wsum[wave] = incl;
        __syncthreads();
        int p = 0;
        if (t < BSZ) {
            int woff = 0;
            for (int w = 0; w < wave; ++w) woff += wsum[w];
            p = woff + incl;
            pref[t + 1] = p;
            if (t == 0) pref[0] = 0;
        }
        __syncthreads();
        if (t < BSZ) deg_cur[t] = p - v;     // cursor = exclusive prefix
        __syncthreads();

#pragma unroll
        for (int it = 0; it < MAXIT; ++it) {
            if (lo + it * 512 + t < hi) {
                int2 rr = r[it];
                int node = (unsigned)rr.x >> 24;
                int d    = rr.x & 0xFFFFFF;
                float hh = __uint_as_float((unsigned)rr.y & 0xFFFF0000u);
                float vv = __uint_as_float((unsigned)rr.y << 16);
                int pos = atomicAdd(&deg_cur[node], 1);
                rec[pos] = make_int2(d, __float_as_int(vv));
                atomicAdd(&hsumS[node], hh);
            }
        }
        __syncthreads();

        for (int n = wave; n < nn; n += 8) {
            const int s = pref[n], e2 = pref[n + 1];
            float a0 = 0.f, a1 = 0.f, a2 = 0.f, a3 = 0.f;
            int j = s;
            for (; j + 4 <= e2; j += 4) {
                int2 q0 = rec[j], q1 = rec[j + 1], q2 = rec[j + 2], q3 = rec[j + 3];
                a0 += __int_as_float(q0.y) * bf2f(h0b[(size_t)q0.x * 64 + lane]);
                a1 += __int_as_float(q1.y) * bf2f(h0b[(size_t)q1.x * 64 + lane]);
                a2 += __int_as_float(q2.y) * bf2f(h0b[(size_t)q2.x * 64 + lane]);
                a3 += __int_as_float(q3.y) * bf2f(h0b[(size_t)q3.x * 64 + lane]);
            }
            for (; j < e2; ++j) {
                int2 q = rec[j];
                a0 += __int_as_float(q.y) * bf2f(h0b[(size_t)q.x * 64 + lane]);
            }
            float acc = (a0 + a1) + (a2 + a3);
            float hs = hsumS[n];
            out[(size_t)(n0 + n) * 64 + lane] = (e2 > s) ? acc / hs : 0.f;
            if (lane == 0) h_sum_g[n0 + n] = hs;
        }
    } else {
        // correctness-only fallback (cnt > CAPB is ~11 sigma; never expected)
        for (int n = wave; n < nn; n += 8) {
            float acc = 0.f, hs = 0.f;
            for (int j = lo; j < hi; ++j) {
                int2 rr = binned[j];
                if (((unsigned)rr.x >> 24) == (unsigned)n) {
                    hs  += __uint_as_float((unsigned)rr.y & 0xFFFF0000u);
                    acc += __uint_as_float((unsigned)rr.y << 16) *
                           bf2f(h0b[(size_t)(rr.x & 0xFFFFFF) * 64 + lane]);
                }
            }
            out[(size_t)(n0 + n) * 64 + lane] = (hs > 0.f) ? acc / hs : 0.f;
            if (lane == 0) h_sum_g[n0 + n] = hs;
        }
    }
}

// ---------------------------------------------------------------------------
// K7: alpha[e] = h_edge[e] / h_sum[src[e]]  (coalesced, x4)
__global__ __launch_bounds__(256) void k_alpha(
    const float* __restrict__ h_edge, const int* __restrict__ src,
    const float* __restrict__ h_sum_g, float* __restrict__ alpha, int E)
{
    int i = blockIdx.x * 256 + threadIdx.x;
    int e = i * 4;
    if (e + 3 < E) {
        float4 h4 = *(const float4*)&h_edge[e];
        int4   s4 = *(const int4*)&src[e];
        float4 a;
        a.x = h4.x / h_sum_g[s4.x];
        a.y = h4.y / h_sum_g[s4.y];
        a.z = h4.z / h_sum_g[s4.z];
        a.w = h4.w / h_sum_g[s4.w];
        *(float4*)&alpha[e] = a;
    } else {
        for (; e < E; ++e) alpha[e] = h_edge[e] / h_sum_g[src[e]];
    }
}

// ---------------------------------------------------------------------------
extern "C" void kernel_launch(void* const* d_in, const int* in_sizes, int n_in,
                              void* d_out, int out_size, void* d_ws, size_t ws_size,
                              hipStream_t stream)
{
    const float* x    = (const float*)d_in[0];
    const int*   ei   = (const int*)d_in[1];
    const float* adj  = (const float*)d_in[2];
    const float* fc_w = (const float*)d_in[3];
    const float* a_w  = (const float*)d_in[4];
    const float* a_b  = (const float*)d_in[5];

    const int N = in_sizes[0] / 128;          // 100000
    const int E = in_sizes[2];                // 1600000
    const int* src = ei;
    const int* dst = ei + E;

    const int NB  = (N + BSZ - 1) >> BSH;     // 782 buckets
    const int NEB = (E + EPB - 1) / EPB;      // 196 edge blocks

    float* out   = (float*)d_out;
    float* alpha = out + (size_t)N * 64;

    char* w = (char*)d_ws;
    auto carve = [&](size_t bytes) {
        char* p = w;
        w += (bytes + 255) & ~(size_t)255;
        return p;
    };
    unsigned short* h0b = (unsigned short*)carve((size_t)N * 64 * 2);
    float* s_src   = (float*)carve((size_t)N * 4);
    float* s_dst   = (float*)carve((size_t)N * 4);
    float* h_edge  = (float*)carve((size_t)E * 4);
    float* h_sum_g = (float*)carve((size_t)N * 4);
    int*   Hist    = (int*)  carve((size_t)NEB * NB * 4);
    int*   Base    = (int*)  carve((size_t)NEB * NB * 4);
    int*   coltot  = (int*)  carve((size_t)NB * 4);
    int*   boff    = (int*)  carve((size_t)(NB + 1) * 4);
    int2*  binned  = (int2*) carve((size_t)E * 8);

    const int tiles  = (N + 15) / 16;          // 6250
    const int lgrid  = (tiles + 3) / 4;        // 1563

    k_linear_mfma<<<lgrid, 256, 0, stream>>>(x, fc_w, a_w, a_b, h0b, s_src, s_dst, N);
    k_edge_h<<<NEB, 512, 0, stream>>>(src, dst, s_src, s_dst, h_edge, Hist, E, NB);
    k_colscan<<<NB, 512, 0, stream>>>(Hist, Base, coltot, NEB, NB);
    k_boff<<<1, 512, 0, stream>>>(coltot, boff, NB, E);
    k_bin<<<NEB, 512, 0, stream>>>(src, dst, adj, h_edge, boff, Base, binned, E, NB);
    k_bucket<<<NB, 512, 0, stream>>>(binned, boff, h0b, out, h_sum_g, N);
    k_alpha<<<(E / 4 + 255) / 256, 256, 0, stream>>>(h_edge, src, h_sum_g, alpha, E);
}

// Round 7
// 152.140 us; speedup vs baseline: 2.8183x; 1.0136x over previous
//
#include <hip/hip_runtime.h>
#include <hip/hip_bf16.h>

// GAT layer, round 7: quad-edge gather in k_bucket (uint2 loads, shfl reduce),
// h_edge intermediate removed (recomputed from L2-resident scores),
// inv_hsum replaces division in k_alpha. MFMA linear unchanged.
// N=100000, F=128, H=64, E=1.6M.

#define LEAKY 0.05f
#define BSH   7                  // nodes per bucket = 128
#define BSZ   128
#define EPB   4096               // edges per segment (hist/bin blocks)
#define MAXIT 5
#define CAPB  (MAXIT * 512)      // 2560 records fast-path cap (mean 2046, +11 sigma)

using bf16x8 = __attribute__((ext_vector_type(8))) __bf16;
using f32x4  = __attribute__((ext_vector_type(4))) float;

__device__ __forceinline__ int wave_scan_incl(int v, int lane) {
#pragma unroll
    for (int off = 1; off < 64; off <<= 1) {
        int u = __shfl_up(v, off);
        if (lane >= off) v += u;
    }
    return v;
}
__device__ __forceinline__ unsigned short f2bf(float f) {   // RNE bf16
    unsigned u = __float_as_uint(f);
    return (unsigned short)((u + 0x7FFF + ((u >> 16) & 1)) >> 16);
}
__device__ __forceinline__ float bf2f(unsigned short u) {
    return __uint_as_float((unsigned)u << 16);
}
__device__ __forceinline__ bf16x8 pack8(const float* p) {
    float4 lo = *(const float4*)p;
    float4 hi = *(const float4*)(p + 4);
    bf16x8 v;
    v[0] = (__bf16)lo.x; v[1] = (__bf16)lo.y; v[2] = (__bf16)lo.z; v[3] = (__bf16)lo.w;
    v[4] = (__bf16)hi.x; v[5] = (__bf16)hi.y; v[6] = (__bf16)hi.z; v[7] = (__bf16)hi.w;
    return v;
}
__device__ __forceinline__ float leaky_exp(float t) {
    t = (t >= 0.f) ? t : LEAKY * t;
    return __expf(t);
}

// ---------------------------------------------------------------------------
// K1: h0b = bf16(x @ fc_w^T) via mfma_f32_16x16x32_bf16; s_src/s_dst from regs.
__global__ __launch_bounds__(256) void k_linear_mfma(
    const float* __restrict__ x, const float* __restrict__ fc_w,
    const float* __restrict__ a_w, const float* __restrict__ a_b,
    unsigned short* __restrict__ h0b, float* __restrict__ s_src,
    float* __restrict__ s_dst, int N)
{
    const int wave = threadIdx.x >> 6, lane = threadIdx.x & 63;
    const int row = lane & 15, grp = lane >> 4;

    bf16x8 bf[4][4];
#pragma unroll
    for (int nt = 0; nt < 4; ++nt) {
        const float* wrow = fc_w + (size_t)(nt * 16 + row) * 128;
#pragma unroll
        for (int kb = 0; kb < 4; ++kb)
            bf[nt][kb] = pack8(wrow + kb * 32 + grp * 8);
    }
    float aw0[4], aw1[4];
#pragma unroll
    for (int nt = 0; nt < 4; ++nt) {
        aw0[nt] = a_w[nt * 16 + row];
        aw1[nt] = a_w[64 + nt * 16 + row];
    }
    const float ab = a_b[0];

    const int tile = blockIdx.x * 4 + wave;
    const int base = tile * 16;
    if (base >= N) return;
    const int node = min(base + row, N - 1);

    bf16x8 af[4];
#pragma unroll
    for (int kb = 0; kb < 4; ++kb)
        af[kb] = pack8(x + (size_t)node * 128 + kb * 32 + grp * 8);

    f32x4 acc[4];
#pragma unroll
    for (int nt = 0; nt < 4; ++nt) acc[nt] = (f32x4){0.f, 0.f, 0.f, 0.f};

#pragma unroll
    for (int nt = 0; nt < 4; ++nt)
#pragma unroll
        for (int kb = 0; kb < 4; ++kb)
            acc[nt] = __builtin_amdgcn_mfma_f32_16x16x32_bf16(
                af[kb], bf[nt][kb], acc[nt], 0, 0, 0);

#pragma unroll
    for (int nt = 0; nt < 4; ++nt)
#pragma unroll
        for (int r = 0; r < 4; ++r) {
            int nrow = base + grp * 4 + r;
            if (nrow < N)
                h0b[(size_t)nrow * 64 + nt * 16 + row] = f2bf(acc[nt][r]);
        }

#pragma unroll
    for (int r = 0; r < 4; ++r) {
        float p0 = 0.f, p1 = 0.f;
#pragma unroll
        for (int nt = 0; nt < 4; ++nt) {
            p0 += acc[nt][r] * aw0[nt];
            p1 += acc[nt][r] * aw1[nt];
        }
#pragma unroll
        for (int off = 1; off < 16; off <<= 1) {
            p0 += __shfl_xor(p0, off);
            p1 += __shfl_xor(p1, off);
        }
        int nrow = base + grp * 4 + r;
        if (row == 0 && nrow < N) { s_src[nrow] = p0 + ab; s_dst[nrow] = p1; }
    }
}

// ---------------------------------------------------------------------------
// K2: per-segment bucket histogram (src only, int4 loads, LDS atomics)
__global__ __launch_bounds__(256) void k_hist(
    const int* __restrict__ src, int* __restrict__ Hist, int E, int NB)
{
    __shared__ int hist[1024];
    for (int b = threadIdx.x; b < NB; b += 256) hist[b] = 0;
    __syncthreads();
    const int e0 = blockIdx.x * EPB;
#pragma unroll
    for (int k = 0; k < EPB / 1024; ++k) {
        int e = e0 + k * 1024 + threadIdx.x * 4;
        if (e + 3 < E) {
            int4 s4 = *(const int4*)&src[e];
            atomicAdd(&hist[s4.x >> BSH], 1);
            atomicAdd(&hist[s4.y >> BSH], 1);
            atomicAdd(&hist[s4.z >> BSH], 1);
            atomicAdd(&hist[s4.w >> BSH], 1);
        } else {
            for (int q = e; q < E; ++q) atomicAdd(&hist[src[q] >> BSH], 1);
        }
    }
    __syncthreads();
    for (int b = threadIdx.x; b < NB; b += 256)
        Hist[blockIdx.x * NB + b] = hist[b];
}

// ---------------------------------------------------------------------------
// K3: column scan of Hist -> Base[seg][b] (excl prefix within column) + coltot
__global__ __launch_bounds__(512) void k_colscan(
    const int* __restrict__ Hist, int* __restrict__ Base,
    int* __restrict__ coltot, int NEB, int NB)
{
    __shared__ int wsum[8];
    const int b = blockIdx.x;
    const int t = threadIdx.x, wave = t >> 6, lane = t & 63;
    int v = (t < NEB) ? Hist[t * NB + b] : 0;
    int incl = wave_scan_incl(v, lane);
    if (lane == 63) wsum[wave] = incl;
    __syncthreads();
    int woff = 0;
    for (int w = 0; w < wave; ++w) woff += wsum[w];
    if (t < NEB) Base[t * NB + b] = woff + incl - v;
    if (t == NEB - 1) coltot[b] = woff + incl;
}

// K4: chunked exclusive scan of coltot[NB] -> boff
__global__ __launch_bounds__(512) void k_boff(
    const int* __restrict__ coltot, int* __restrict__ boff, int NB, int E)
{
    __shared__ int wsum[8];
    __shared__ int s_carry;
    const int t = threadIdx.x, wave = t >> 6, lane = t & 63;
    if (t == 0) s_carry = 0;
    __syncthreads();
    for (int base = 0; base < NB; base += 512) {
        int idx = base + t;
        int orig = (idx < NB) ? coltot[idx] : 0;
        int incl = wave_scan_incl(orig, lane);
        if (lane == 63) wsum[wave] = incl;
        __syncthreads();
        int woff = 0;
        for (int w = 0; w < wave; ++w) woff += wsum[w];
        int carry = s_carry;
        if (idx < NB) boff[idx] = carry + woff + incl - orig;
        __syncthreads();
        if (t == 511) s_carry = carry + woff + incl;
        __syncthreads();
    }
    if (t == 0) boff[NB] = E;
}

// ---------------------------------------------------------------------------
// K5: bin edges; h recomputed from scores; record {dst|srclow<<24, h_bf|v_bf}
__global__ __launch_bounds__(256) void k_bin(
    const int* __restrict__ src, const int* __restrict__ dst,
    const float* __restrict__ adj,
    const float* __restrict__ s_src, const float* __restrict__ s_dst,
    const int* __restrict__ boff, const int* __restrict__ Base,
    int2* __restrict__ binned, int E, int NB)
{
    __shared__ int cur[1024];
    for (int b = threadIdx.x; b < NB; b += 256)
        cur[b] = boff[b] + Base[blockIdx.x * NB + b];
    __syncthreads();
    const int e0 = blockIdx.x * EPB;
#pragma unroll
    for (int k = 0; k < EPB / 1024; ++k) {
        int e = e0 + k * 1024 + threadIdx.x * 4;
        if (e + 3 < E) {
            int4   s4 = *(const int4*)&src[e];
            int4   d4 = *(const int4*)&dst[e];
            float4 a4 = *(const float4*)&adj[e];
#pragma unroll
            for (int q = 0; q < 4; ++q) {
                int s = (&s4.x)[q], d = (&d4.x)[q];
                float h = leaky_exp(s_src[s] + s_dst[d]);
                float v = h * (&a4.x)[q];
                unsigned hv = ((unsigned)f2bf(h) << 16) | f2bf(v);
                int w0 = d | ((s & (BSZ - 1)) << 24);
                int pos = atomicAdd(&cur[s >> BSH], 1);
                binned[pos] = make_int2(w0, (int)hv);
            }
        } else {
            for (int q = e; q < E; ++q) {
                int s = src[q], d = dst[q];
                float h = leaky_exp(s_src[s] + s_dst[d]);
                float v = h * adj[q];
                unsigned hv = ((unsigned)f2bf(h) << 16) | f2bf(v);
                int w0 = d | ((s & (BSZ - 1)) << 24);
                int pos = atomicAdd(&cur[s >> BSH], 1);
                binned[pos] = make_int2(w0, (int)hv);
            }
        }
    }
}

// ---------------------------------------------------------------------------
// K6: per-bucket LDS CSR build + quad-edge fused gather.
// Gather lanes: eslot=lane>>4 (edge in quad), fq=lane&15 (feature quad).
__global__ __launch_bounds__(512) void k_bucket(
    const int2* __restrict__ binned, const int* __restrict__ boff,
    const unsigned short* __restrict__ h0b, float* __restrict__ out,
    float* __restrict__ inv_hsum_g, int N)
{
    __shared__ int   deg_cur[BSZ];
    __shared__ int   pref[BSZ + 1];
    __shared__ float hsumS[BSZ];
    __shared__ int2  rec[CAPB];       // {dst, val_fp32_bits}
    __shared__ int   wsum[8];

    const int b  = blockIdx.x;
    const int lo = boff[b], hi = boff[b + 1], cnt = hi - lo;
    const int n0 = b << BSH;
    const int nn = min(BSZ, N - n0);
    const int t = threadIdx.x, wave = t >> 6, lane = t & 63;

    if (t < BSZ) { deg_cur[t] = 0; hsumS[t] = 0.f; }
    __syncthreads();

    if (cnt <= CAPB) {
        int2 r[MAXIT];
#pragma unroll
        for (int it = 0; it < MAXIT; ++it) {
            int j = lo + it * 512 + t;
            if (j < hi) r[it] = binned[j];
        }
#pragma unroll
        for (int it = 0; it < MAXIT; ++it)
            if (lo + it * 512 + t < hi)
                atomicAdd(&deg_cur[(unsigned)r[it].x >> 24], 1);
        __syncthreads();

        int v = (t < BSZ) ? deg_cur[t] : 0;
        int incl = wave_scan_incl(v, lane);
        if (t < BSZ && lane == 63) wsum[wave] = incl;
        __syncthreads();
        int p = 0;
        if (t < BSZ) {
            int woff = 0;
            for (int w = 0; w < wave; ++w) woff += wsum[w];
            p = woff + incl;
            pref[t + 1] = p;
            if (t == 0) pref[0] = 0;
        }
        __syncthreads();
        if (t < BSZ) deg_cur[t] = p - v;
        __syncthreads();

#pragma unroll
        for (int it = 0; it < MAXIT; ++it) {
            if (lo + it * 512 + t < hi) {
                int2 rr = r[it];
                int node = (unsigned)rr.x >> 24;
                int d    = rr.x & 0xFFFFFF;
                float hh = __uint_as_float((unsigned)rr.y & 0xFFFF0000u);
                float vv = __uint_as_float((unsigned)rr.y << 16);
                int pos = atomicAdd(&deg_cur[node], 1);
                rec[pos] = make_int2(d, __float_as_int(vv));
                atomicAdd(&hsumS[node], hh);
            }
        }
        __syncthreads();

        const int eslot = lane >> 4, fq = lane & 15;
        for (int n = wave; n < nn; n += 8) {
            const int s = pref[n], e2 = pref[n + 1];
            float a0[4] = {0.f, 0.f, 0.f, 0.f};
            float a1[4] = {0.f, 0.f, 0.f, 0.f};
            for (int base2 = s; base2 < e2; base2 += 8) {
                int idxA = base2 + eslot;
                int idxB = base2 + 4 + eslot;
                bool vA = idxA < e2, vB = idxB < e2;
                int2 rA = rec[vA ? idxA : s];
                int2 rB = rec[vB ? idxB : s];
                float valA = vA ? __int_as_float(rA.y) : 0.f;
                float valB = vB ? __int_as_float(rB.y) : 0.f;
                uint2 uA = *(const uint2*)(h0b + (size_t)rA.x * 64 + fq * 4);
                uint2 uB = *(const uint2*)(h0b + (size_t)rB.x * 64 + fq * 4);
                a0[0] += valA * __uint_as_float(uA.x << 16);
                a0[1] += valA * __uint_as_float(uA.x & 0xFFFF0000u);
                a0[2] += valA * __uint_as_float(uA.y << 16);
                a0[3] += valA * __uint_as_float(uA.y & 0xFFFF0000u);
                a1[0] += valB * __uint_as_float(uB.x << 16);
                a1[1] += valB * __uint_as_float(uB.x & 0xFFFF0000u);
                a1[2] += valB * __uint_as_float(uB.y << 16);
                a1[3] += valB * __uint_as_float(uB.y & 0xFFFF0000u);
            }
#pragma unroll
            for (int k = 0; k < 4; ++k) {
                float vv = a0[k] + a1[k];
                vv += __shfl_xor(vv, 16);
                vv += __shfl_xor(vv, 32);
                a0[k] = vv;
            }
            const bool has = (e2 > s);
            float hs  = hsumS[n];
            float inv = has ? 1.0f / hs : 0.f;
            if (lane < 16) {
                float4 o;
                o.x = a0[0] * inv; o.y = a0[1] * inv;
                o.z = a0[2] * inv; o.w = a0[3] * inv;
                *(float4*)&out[(size_t)(n0 + n) * 64 + fq * 4] = o;
            }
            if (lane == 0) inv_hsum_g[n0 + n] = inv;
        }
    } else {
        // correctness-only fallback (cnt > CAPB is ~11 sigma; never expected)
        for (int n = wave; n < nn; n += 8) {
            float acc = 0.f, hs = 0.f;
            for (int j = lo; j < hi; ++j) {
                int2 rr = binned[j];
                if (((unsigned)rr.x >> 24) == (unsigned)n) {
                    hs  += __uint_as_float((unsigned)rr.y & 0xFFFF0000u);
                    acc += __uint_as_float((unsigned)rr.y << 16) *
                           bf2f(h0b[(size_t)(rr.x & 0xFFFFFF) * 64 + lane]);
                }
            }
            float inv = (hs > 0.f) ? 1.0f / hs : 0.f;
            out[(size_t)(n0 + n) * 64 + lane] = acc * inv;
            if (lane == 0) inv_hsum_g[n0 + n] = inv;
        }
    }
}

// ---------------------------------------------------------------------------
// K7: alpha[e] = h(e) * inv_hsum[src[e]]  (h recomputed; coalesced, x4)
__global__ __launch_bounds__(256) void k_alpha(
    const int* __restrict__ src, const int* __restrict__ dst,
    const float* __restrict__ s_src, const float* __restrict__ s_dst,
    const float* __restrict__ inv_hsum_g, float* __restrict__ alpha, int E)
{
    int i = blockIdx.x * 256 + threadIdx.x;
    int e = i * 4;
    if (e + 3 < E) {
        int4 s4 = *(const int4*)&src[e];
        int4 d4 = *(const int4*)&dst[e];
        float4 a;
        a.x = leaky_exp(s_src[s4.x] + s_dst[d4.x]) * inv_hsum_g[s4.x];
        a.y = leaky_exp(s_src[s4.y] + s_dst[d4.y]) * inv_hsum_g[s4.y];
        a.z = leaky_exp(s_src[s4.z] + s_dst[d4.z]) * inv_hsum_g[s4.z];
        a.w = leaky_exp(s_src[s4.w] + s_dst[d4.w]) * inv_hsum_g[s4.w];
        *(float4*)&alpha[e] = a;
    } else {
        for (; e < E; ++e)
            alpha[e] = leaky_exp(s_src[src[e]] + s_dst[dst[e]]) * inv_hsum_g[src[e]];
    }
}

// ---------------------------------------------------------------------------
extern "C" void kernel_launch(void* const* d_in, const int* in_sizes, int n_in,
                              void* d_out, int out_size, void* d_ws, size_t ws_size,
                              hipStream_t stream)
{
    const float* x    = (const float*)d_in[0];
    const int*   ei   = (const int*)d_in[1];
    const float* adj  = (const float*)d_in[2];
    const float* fc_w = (const float*)d_in[3];
    const float* a_w  = (const float*)d_in[4];
    const float* a_b  = (const float*)d_in[5];

    const int N = in_sizes[0] / 128;          // 100000
    const int E = in_sizes[2];                // 1600000
    const int* src = ei;
    const int* dst = ei + E;

    const int NB  = (N + BSZ - 1) >> BSH;     // 782 buckets
    const int NEB = (E + EPB - 1) / EPB;      // 391 segments

    float* out   = (float*)d_out;
    float* alpha = out + (size_t)N * 64;

    char* w = (char*)d_ws;
    auto carve = [&](size_t bytes) {
        char* p = w;
        w += (bytes + 255) & ~(size_t)255;
        return p;
    };
    unsigned short* h0b = (unsigned short*)carve((size_t)N * 64 * 2);
    float* s_src   = (float*)carve((size_t)N * 4);
    float* s_dst   = (float*)carve((size_t)N * 4);
    float* inv_hs  = (float*)carve((size_t)N * 4);
    int*   Hist    = (int*)  carve((size_t)NEB * NB * 4);
    int*   Base    = (int*)  carve((size_t)NEB * NB * 4);
    int*   coltot  = (int*)  carve((size_t)NB * 4);
    int*   boff    = (int*)  carve((size_t)(NB + 1) * 4);
    int2*  binned  = (int2*) carve((size_t)E * 8);

    const int tiles = (N + 15) / 16;
    const int lgrid = (tiles + 3) / 4;

    k_linear_mfma<<<lgrid, 256, 0, stream>>>(x, fc_w, a_w, a_b, h0b, s_src, s_dst, N);
    k_hist<<<NEB, 256, 0, stream>>>(src, Hist, E, NB);
    k_colscan<<<NB, 512, 0, stream>>>(Hist, Base, coltot, NEB, NB);
    k_boff<<<1, 512, 0, stream>>>(coltot, boff, NB, E);
    k_bin<<<NEB, 256, 0, stream>>>(src, dst, adj, s_src, s_dst, boff, Base,
                                   binned, E, NB);
    k_bucket<<<NB, 512, 0, stream>>>(binned, boff, h0b, out, inv_hs, N);
    k_alpha<<<(E / 4 + 255) / 256, 256, 0, stream>>>(src, dst, s_src, s_dst,
                                                     inv_hs, alpha, E);
}